// Round 13
// baseline (134.991 us; speedup 1.0000x reference)
//
#include <hip/hip_runtime.h>
#include <math.h>
#include <stdint.h>

#define BB   2
#define NN   2048
#define HH   8
#define DD   64
#define EE   512
#define DM1  63
#define KSP  4

typedef _Float16 half8  __attribute__((ext_vector_type(8)));
typedef __fp16   fp16x2 __attribute__((ext_vector_type(2)));
typedef float    floatx4 __attribute__((ext_vector_type(4)));

__device__ __forceinline__ uint32_t pkh2(float a, float b) {
    union { fp16x2 h; uint32_t u; } uu;
    uu.h = __builtin_amdgcn_cvt_pkrtz(a, b);
    return uu.u;
}
__device__ __forceinline__ half8 as_half8(uint4 u) {
    union { uint4 u; half8 h; } uu; uu.u = u; return uu.h;
}

// ---------------------------------------------------------------------------
// Kernel 1: QKV MFMA projection + lift, v2.
// W B-fragments load DIRECTLY from global fp32 (wave-private rows — the LDS
// round-trip had zero reuse) with inline cvt + row-63 zero mask.
// X tile (block-shared) stays in LDS, double-buffered -> ONE barrier/iter.
// vT written sigma-permuted (s = q*8+nt2*4+r <-> kv = nt2*16+q*4+r).
// ---------------------------------------------------------------------------
__global__ __launch_bounds__(256, 3) void qkv_mfma(
    const float* __restrict__ Xq, const float* __restrict__ Xs,
    const float* __restrict__ Wq, const float* __restrict__ Wk,
    const float* __restrict__ Wv,
    const float* __restrict__ Wqb, const float* __restrict__ Wkb,
    const float* __restrict__ Wvb, const float* __restrict__ scale_p,
    _Float16* __restrict__ q16, _Float16* __restrict__ k16,
    _Float16* __restrict__ vT16)
{
    const int mtb = blockIdx.x;   // token tile
    const int hp  = blockIdx.y;   // head pair 0..3
    const int mat = blockIdx.z;
    const int t    = threadIdx.x;
    const int w    = t >> 6;
    const int lane = t & 63;
    const int l15  = lane & 15;
    const int quad = lane >> 4;

    __shared__ alignas(16) char smem[18432];   // X dbuf 2x9216; epilogue alias
    __shared__ float psum[64][4];
    _Float16 (*Osh)[136] = (_Float16(*)[136])smem;   // 17408 B alias
    _Float16 (*OshT)[72] = (_Float16(*)[72])smem;    // 18432 B alias

    const float* X    = (mat == 0) ? Xq : Xs;
    const float* W    = (mat == 0) ? Wq : (mat == 1 ? Wk : Wv);
    const float* bias = (mat == 0) ? Wqb : (mat == 1 ? Wkb : Wvb);
    const int tok0 = mtb * 64;

    floatx4 acc[4][2];
#pragma unroll
    for (int mt = 0; mt < 4; mt++)
#pragma unroll
        for (int nt = 0; nt < 2; nt++) acc[mt][nt] = (floatx4){0.f,0.f,0.f,0.f};

    // W fragment row pointers + validity (wave-private rows)
    const float* wrow[2];
    float wmask[2];
#pragma unroll
    for (int nt = 0; nt < 2; nt++) {
        int col = w * 32 + nt * 16 + l15;
        int head = col >> 6, j = col & 63;
        wmask[nt] = (j < DM1) ? 1.f : 0.f;
        int jj = (j < DM1) ? j : 0;
        wrow[nt] = W + (size_t)((hp * 2 + head) * DM1 + jj) * EE;
    }

    // prefetch X chunk 0
    float4 pxa[2], pxb[2];
#pragma unroll
    for (int ls = 0; ls < 2; ls++) {
        int g = t + 256 * ls, r = g >> 3, c = g & 7;
        const float* p = X + (size_t)(tok0 + r) * EE + c * 8;
        pxa[ls] = *(const float4*)p;
        pxb[ls] = *(const float4*)(p + 4);
    }
    // prefetch W frags chunk 0
    float4 wfa[2][2], wfb[2][2];
#pragma unroll
    for (int nt = 0; nt < 2; nt++)
#pragma unroll
        for (int kk = 0; kk < 2; kk++) {
            const float* p = wrow[nt] + kk * 32 + quad * 8;
            wfa[nt][kk] = *(const float4*)p;
            wfb[nt][kk] = *(const float4*)(p + 4);
        }
    // commit X chunk 0 into buf 0
#pragma unroll
    for (int ls = 0; ls < 2; ls++) {
        int g = t + 256 * ls, r = g >> 3, c = g & 7;
        uint4 h;
        h.x = pkh2(pxa[ls].x, pxa[ls].y); h.y = pkh2(pxa[ls].z, pxa[ls].w);
        h.z = pkh2(pxb[ls].x, pxb[ls].y); h.w = pkh2(pxb[ls].z, pxb[ls].w);
        *(uint4*)(smem + (size_t)r * 144 + c * 16) = h;
    }
    __syncthreads();

    for (int it = 0; it < 8; it++) {
        const int buf = it & 1;
        _Float16 (*Xsh)[72] = (_Float16(*)[72])(smem + buf * 9216);

        // build B-frags from current W regs (row-63 masked)
        half8 bfr[2][2];
#pragma unroll
        for (int nt = 0; nt < 2; nt++) {
            float m = wmask[nt];
#pragma unroll
            for (int kk = 0; kk < 2; kk++) {
                uint4 u;
                u.x = pkh2(wfa[nt][kk].x * m, wfa[nt][kk].y * m);
                u.y = pkh2(wfa[nt][kk].z * m, wfa[nt][kk].w * m);
                u.z = pkh2(wfb[nt][kk].x * m, wfb[nt][kk].y * m);
                u.w = pkh2(wfb[nt][kk].z * m, wfb[nt][kk].w * m);
                bfr[nt][kk] = as_half8(u);
            }
        }

        if (it + 1 < 8) {   // prefetch next chunk (X + W frags)
            int ek = (it + 1) * 64;
#pragma unroll
            for (int ls = 0; ls < 2; ls++) {
                int g = t + 256 * ls, r = g >> 3, c = g & 7;
                const float* p = X + (size_t)(tok0 + r) * EE + ek + c * 8;
                pxa[ls] = *(const float4*)p;
                pxb[ls] = *(const float4*)(p + 4);
            }
#pragma unroll
            for (int nt = 0; nt < 2; nt++)
#pragma unroll
                for (int kk = 0; kk < 2; kk++) {
                    const float* p = wrow[nt] + ek + kk * 32 + quad * 8;
                    wfa[nt][kk] = *(const float4*)p;
                    wfb[nt][kk] = *(const float4*)(p + 4);
                }
        }

        // MFMA on current X buffer
#pragma unroll
        for (int kk = 0; kk < 2; kk++) {
            half8 a[4];
#pragma unroll
            for (int mt = 0; mt < 4; mt++)
                a[mt] = *(const half8*)&Xsh[mt * 16 + l15][kk * 32 + quad * 8];
#pragma unroll
            for (int nt = 0; nt < 2; nt++)
#pragma unroll
                for (int mt = 0; mt < 4; mt++)
                    acc[mt][nt] = __builtin_amdgcn_mfma_f32_16x16x32_f16(
                        a[mt], bfr[nt][kk], acc[mt][nt], 0, 0, 0);
        }

        // commit next X into the OTHER buffer, single barrier
        if (it + 1 < 8) {
            char* xd = smem + (1 - buf) * 9216;
#pragma unroll
            for (int ls = 0; ls < 2; ls++) {
                int g = t + 256 * ls, r = g >> 3, c = g & 7;
                uint4 h;
                h.x = pkh2(pxa[ls].x, pxa[ls].y); h.y = pkh2(pxa[ls].z, pxa[ls].w);
                h.z = pkh2(pxb[ls].x, pxb[ls].y); h.w = pkh2(pxb[ls].z, pxb[ls].w);
                *(uint4*)(xd + (size_t)r * 144 + c * 16) = h;
            }
        }
        __syncthreads();
    }
    // final barrier passed: all X reads done -> Osh/OshT alias safe

    const float st   = 2.0f / scale_p[0];
    const float fmul = (mat == 0) ? st : 1.0f;

    float vals[4][2][4];
    float sqp[4][4];
#pragma unroll
    for (int mt = 0; mt < 4; mt++)
#pragma unroll
        for (int r = 0; r < 4; r++) sqp[mt][r] = 0.f;

#pragma unroll
    for (int mt = 0; mt < 4; mt++)
#pragma unroll
        for (int nt = 0; nt < 2; nt++) {
            int col = w * 32 + nt * 16 + l15;
            int head = col >> 6, j = col & 63;
            float bb = (j < DM1) ? bias[(hp * 2 + head) * DM1 + j] : 0.f;
#pragma unroll
            for (int r = 0; r < 4; r++) {
                float vv = acc[mt][nt][r] + bb;
                if (j >= DM1) vv = 0.f;
                vals[mt][nt][r] = vv;
                sqp[mt][r] += vv * vv;
            }
        }
#pragma unroll
    for (int mt = 0; mt < 4; mt++)
#pragma unroll
        for (int r = 0; r < 4; r++) {
            float s = sqp[mt][r];
            s += __shfl_xor(s, 1, 64); s += __shfl_xor(s, 2, 64);
            s += __shfl_xor(s, 4, 64); s += __shfl_xor(s, 8, 64);
            if (l15 == 0) psum[mt * 16 + quad * 4 + r][w] = s;
        }

    if (mat < 2) {
#pragma unroll
        for (int mt = 0; mt < 4; mt++)
#pragma unroll
            for (int nt = 0; nt < 2; nt++) {
                int col = w * 32 + nt * 16 + l15;
                int head = col >> 6, j = col & 63;
                if (j < DM1) {
                    int dc = head * 64 + 1 + j;
#pragma unroll
                    for (int r = 0; r < 4; r++)
                        Osh[mt * 16 + quad * 4 + r][dc] = (_Float16)(vals[mt][nt][r] * fmul);
                }
            }
    } else {
#pragma unroll
        for (int mt = 0; mt < 4; mt++)
#pragma unroll
            for (int nt = 0; nt < 2; nt++) {
                int col = w * 32 + nt * 16 + l15;
                uint2 pu;
                pu.x = pkh2(vals[mt][nt][0], vals[mt][nt][1]);
                pu.y = pkh2(vals[mt][nt][2], vals[mt][nt][3]);
                *(uint2*)&OshT[col][mt * 16 + quad * 4] = pu;
            }
    }
    __syncthreads();
    if (t < 64) {
        float tsA = sqrtf(psum[t][0] + psum[t][1] + 1.0f);
        float tsB = sqrtf(psum[t][2] + psum[t][3] + 1.0f);
        if (mat < 2) {
            float tm = (mat == 0) ? -st : 1.0f;
            Osh[t][0]  = (_Float16)(tsA * tm);
            Osh[t][64] = (_Float16)(tsB * tm);
        } else {
            OshT[63][t]  = (_Float16)tsA;
            OshT[127][t] = (_Float16)tsB;
        }
    }
    __syncthreads();

    const int bI = tok0 >> 11, n0 = tok0 & 2047;
    if (mat < 2) {
        _Float16* O = (mat == 0) ? q16 : k16;
#pragma unroll
        for (int ls = 0; ls < 4; ls++) {
            int s = t + 256 * ls, r = s >> 4, c = s & 15, head = c >> 3;
            size_t bh = (size_t)(bI * HH + hp * 2 + head);
            *(uint4*)&O[(bh * NN + n0 + r) * DD + (c & 7) * 8] = *(const uint4*)&Osh[r][c * 8];
        }
    } else {
        // sigma-permuted vT write: each uint4 splits into two uint2 granules
#pragma unroll
        for (int ls = 0; ls < 4; ls++) {
            int s = t + 256 * ls, df = s >> 3, c = s & 7;
            int head = df >> 6, d = df & 63;
            int rr = head * 64 + ((d + 63) & 63);   // d=0 -> row 63 (time slot)
            size_t bh = (size_t)(bI * HH + hp * 2 + head);
            uint4 v = *(const uint4*)&OshT[rr][c * 8];
            int cc = c & 3, hf = c >> 2;
            int sA = hf * 32 + ((2 * cc) & 3) * 8 + (cc >> 1) * 4;
            int sB = hf * 32 + ((2 * cc + 1) & 3) * 8 + (cc >> 1) * 4;
            _Float16* vrow = &vT16[(bh * DD + d) * NN + n0];
            *(uint2*)&vrow[sA] = make_uint2(v.x, v.y);
            *(uint2*)&vrow[sB] = make_uint2(v.z, v.w);
        }
    }
}

// ---------------------------------------------------------------------------
// Kernel 2: Lorentz flash attention v13 — identical to R11's winner: no-P
// in-register path (sigma V), KSP=4, grid (8,16,4)=512 blocks=2/CU, 8 iters,
// double-buffered K/V, one barrier/iter, 64 q-rows/wave.
// ---------------------------------------------------------------------------
__global__ __launch_bounds__(256, 2) void lorentz_attn_v13(
    const _Float16* __restrict__ q16, const _Float16* __restrict__ k16,
    const _Float16* __restrict__ vT16,
    _Float16* __restrict__ Odh, float* __restrict__ Ors)
{
    const int qt = blockIdx.x;    // 256 q-rows per block
    const int bh = blockIdx.y;
    const int ks = blockIdx.z;    // split-K quarter
    const int t    = threadIdx.x;
    const int w    = t >> 6;
    const int lane = t & 63;
    const int l15  = lane & 15;
    const int quad = lane >> 4;

    __shared__ alignas(16) char smem[36864];
    // K bufs [2][64][72] @ 0 ; VT bufs [2][64][72] @ 18432

    const _Float16* kb = k16  + (size_t)bh * NN * DD;
    const _Float16* vb = vT16 + (size_t)bh * DD * NN;
    const int base = ks * 8;

    // Q B-fragments: wave w owns q-rows qt*256 + w*64 + mt*16 + [0,16)
    half8 qb[4][2];
#pragma unroll
    for (int mt = 0; mt < 4; mt++) {
        const _Float16* qrow = q16 +
            ((size_t)bh * NN + qt * 256 + w * 64 + mt * 16 + l15) * DD;
        qb[mt][0] = *(const half8*)&qrow[quad * 8];
        qb[mt][1] = *(const half8*)&qrow[32 + quad * 8];
    }

    half8 vones;
#pragma unroll
    for (int i = 0; i < 8; i++) vones[i] = (_Float16)1.0f;

    // prefetch + commit tile 0 into buf 0
    uint4 pk[2], pv[2];
#pragma unroll
    for (int ls = 0; ls < 2; ls++) {
        int s = t + 256 * ls, r = s >> 3, c = s & 7;
        pk[ls] = *(const uint4*)&kb[((size_t)base * 64 + r) * DD + c * 8];
        pv[ls] = *(const uint4*)&vb[(size_t)r * NN + base * 64 + c * 8];
    }
#pragma unroll
    for (int ls = 0; ls < 2; ls++) {
        int s = t + 256 * ls, r = s >> 3, c = s & 7;
        *(uint4*)(smem +         (size_t)r * 144 + c * 16) = pk[ls];
        *(uint4*)(smem + 18432 + (size_t)r * 144 + c * 16) = pv[ls];
    }
    __syncthreads();

    floatx4 oacc[4][5];
#pragma unroll
    for (int mt = 0; mt < 4; mt++)
#pragma unroll
        for (int nt = 0; nt < 5; nt++) oacc[mt][nt] = (floatx4){0.f,0.f,0.f,0.f};

    for (int i = 0; i < 8; i++) {
        const int kt = base + i;
        const int buf = i & 1;
        _Float16 (*Ks)[72]  = (_Float16(*)[72])(smem + buf * 9216);
        _Float16 (*VTs)[72] = (_Float16(*)[72])(smem + 18432 + buf * 9216);

        if (i + 1 < 8) {   // prefetch next tile into registers
#pragma unroll
            for (int ls = 0; ls < 2; ls++) {
                int s = t + 256 * ls, r = s >> 3, c = s & 7;
                pk[ls] = *(const uint4*)&kb[((size_t)(kt + 1) * 64 + r) * DD + c * 8];
                pv[ls] = *(const uint4*)&vb[(size_t)r * NN + (kt + 1) * 64 + c * 8];
            }
        }

#pragma unroll
        for (int half = 0; half < 2; half++) {
            // ---- S^T for this kv-half (nt = half*2 + nt2) ----
            floatx4 sacc[2][4];
#pragma unroll
            for (int nt2 = 0; nt2 < 2; nt2++) {
#pragma unroll
                for (int mt = 0; mt < 4; mt++) sacc[nt2][mt] = (floatx4){0.f,0.f,0.f,0.f};
                const int nt = half * 2 + nt2;
#pragma unroll
                for (int kk = 0; kk < 2; kk++) {
                    half8 kf = *(const half8*)&Ks[nt * 16 + l15][kk * 32 + quad * 8];
#pragma unroll
                    for (int mt = 0; mt < 4; mt++)
                        sacc[nt2][mt] = __builtin_amdgcn_mfma_f32_16x16x32_f16(
                            kf, qb[mt][kk], sacc[nt2][mt], 0, 0, 0);
                }
            }
            // ---- exp + pack in-register: this IS the PV A-fragment ----
            half8 pa[4];
#pragma unroll
            for (int mt = 0; mt < 4; mt++) {
                uint4 u;
                u.x = pkh2(__expf(sacc[0][mt][0]), __expf(sacc[0][mt][1]));
                u.y = pkh2(__expf(sacc[0][mt][2]), __expf(sacc[0][mt][3]));
                u.z = pkh2(__expf(sacc[1][mt][0]), __expf(sacc[1][mt][1]));
                u.w = pkh2(__expf(sacc[1][mt][2]), __expf(sacc[1][mt][3]));
                pa[mt] = as_half8(u);
            }
            // ---- O += P . [V_sigma ; 1] for this half (K=32) ----
#pragma unroll
            for (int nt = 0; nt < 4; nt++) {
                half8 vf = *(const half8*)&VTs[nt * 16 + l15][half * 32 + quad * 8];
#pragma unroll
                for (int mt = 0; mt < 4; mt++)
                    oacc[mt][nt] = __builtin_amdgcn_mfma_f32_16x16x32_f16(
                        pa[mt], vf, oacc[mt][nt], 0, 0, 0);
            }
#pragma unroll
            for (int mt = 0; mt < 4; mt++)
                oacc[mt][4] = __builtin_amdgcn_mfma_f32_16x16x32_f16(
                    pa[mt], vones, oacc[mt][4], 0, 0, 0);
        }

        // ---- commit next tile into the OTHER buffer, single barrier ----
        if (i + 1 < 8) {
            char* kd = smem +         (1 - buf) * 9216;
            char* vd = smem + 18432 + (1 - buf) * 9216;
#pragma unroll
            for (int ls = 0; ls < 2; ls++) {
                int s = t + 256 * ls, r = s >> 3, c = s & 7;
                *(uint4*)(kd + (size_t)r * 144 + c * 16) = pk[ls];
                *(uint4*)(vd + (size_t)r * 144 + c * 16) = pv[ls];
            }
        }
        __syncthreads();
    }

    // ---- coalesced f16 dump via per-wave f32 slab (reuse K/V LDS) ----
    const size_t obase = (((size_t)ks * 16 + bh) * NN + qt * 256 + w * 64);
    float* slab = (float*)(smem + w * 4608);   // 16x68 f32 = 4352 B per wave
#pragma unroll
    for (int mt = 0; mt < 4; mt++) {
#pragma unroll
        for (int nt = 0; nt < 4; nt++)
#pragma unroll
            for (int r = 0; r < 4; r++)
                slab[(quad * 4 + r) * 68 + nt * 16 + l15] = oacc[mt][nt][r];
        // wave-local slab; compiler inserts lgkm waits
#pragma unroll
        for (int i = 0; i < 4; i++) {
            int s = lane + 64 * i, row = s >> 4, c4 = (s & 15) * 4;
            float4 v = *(const float4*)&slab[row * 68 + c4];
            uint2 pu;
            pu.x = pkh2(v.x, v.y);
            pu.y = pkh2(v.z, v.w);
            *(uint2*)&Odh[(obase + mt * 16 + row) * 64 + c4] = pu;
        }
        if (l15 == 0) {
#pragma unroll
            for (int r = 0; r < 4; r++)
                Ors[obase + mt * 16 + quad * 4 + r] = oacc[mt][4][r];
        }
    }
}

// ---------------------------------------------------------------------------
// Kernel 3: 4-way split-K merge + per-head Lorentzian centroid + head mean +
// final centroid. One wave per token; lane = d.
// ---------------------------------------------------------------------------
__global__ __launch_bounds__(256) void merge_centroid(
    const _Float16* __restrict__ Odh, const float* __restrict__ Ors,
    float* __restrict__ out)
{
    const int t    = threadIdx.x;
    const int tok  = blockIdx.x * 4 + (t >> 6);
    const int lane = t & 63;
    const int b = tok >> 11;
    const int n = tok & 2047;

    float m = 0.f;
#pragma unroll
    for (int h = 0; h < HH; h++) {
        const size_t bh = (size_t)(b * HH + h);
        float o = 0.f, rs = 0.f;
#pragma unroll
        for (int ksp = 0; ksp < KSP; ksp++) {
            const size_t row = ((size_t)ksp * 16 + bh) * NN + n;
            o  += (float)Odh[row * 64 + lane];
            rs += Ors[row];
        }
        float a  = o / rs;
        float ssq = a * a;
#pragma unroll
        for (int off = 32; off > 0; off >>= 1)
            ssq += __shfl_xor(ssq, off, 64);
        float a0 = __shfl(a, 0, 64);           // d=0 = time
        float inner = ssq - 2.0f * a0 * a0;
        float f = rsqrtf(fmaxf(fabsf(inner), 1e-8f));
        m += a * f;
    }
    m *= 0.125f;

    float sq = m * m;
#pragma unroll
    for (int off = 32; off > 0; off >>= 1)
        sq += __shfl_xor(sq, off, 64);
    float m0 = __shfl(m, 0, 64);
    float inner = sq - 2.0f * m0 * m0;
    float f = rsqrtf(fmaxf(fabsf(inner), 1e-8f));
    out[(size_t)tok * DD + lane] = m * f;
}

extern "C" void kernel_launch(void* const* d_in, const int* in_sizes, int n_in,
                              void* d_out, int out_size, void* d_ws, size_t ws_size,
                              hipStream_t stream)
{
    const float* Xq  = (const float*)d_in[0];
    const float* Xs  = (const float*)d_in[1];
    const float* Wq  = (const float*)d_in[2];
    const float* Wqb = (const float*)d_in[3];
    const float* Wk  = (const float*)d_in[4];
    const float* Wkb = (const float*)d_in[5];
    const float* Wv  = (const float*)d_in[6];
    const float* Wvb = (const float*)d_in[7];
    const float* sc  = (const float*)d_in[8];
    float* out = (float*)d_out;

    const size_t QSZ = (size_t)BB * HH * NN * DD;   // 2,097,152 halves
    _Float16* q16  = (_Float16*)d_ws;
    _Float16* k16  = q16 + QSZ;
    _Float16* vT16 = k16 + QSZ;                     // 12 MB f16
    _Float16* Odh  = vT16 + QSZ;                    // 4*16*2048*64 f16 = 16.8 MB
    float* Ors = (float*)(Odh + (size_t)KSP * 16 * NN * 64);  // 512 KB

    qkv_mfma<<<dim3(64, 4, 3), 256, 0, stream>>>(Xq, Xs, Wq, Wk, Wv,
                                                 Wqb, Wkb, Wvb, sc,
                                                 q16, k16, vT16);
    lorentz_attn_v13<<<dim3(8, 16, KSP), 256, 0, stream>>>(q16, k16, vT16, Odh, Ors);
    merge_centroid<<<(BB * NN) / 4, 256, 0, stream>>>(Odh, Ors, out);
}

// Round 14
// 126.153 us; speedup vs baseline: 1.0701x; 1.0701x over previous
//
#include <hip/hip_runtime.h>
#include <math.h>
#include <stdint.h>

#define BB   2
#define NN   2048
#define HH   8
#define DD   64
#define EE   512
#define DM1  63
#define KSP  4

typedef _Float16 half8  __attribute__((ext_vector_type(8)));
typedef __fp16   fp16x2 __attribute__((ext_vector_type(2)));
typedef float    floatx4 __attribute__((ext_vector_type(4)));

__device__ __forceinline__ uint32_t pkh2(float a, float b) {
    union { fp16x2 h; uint32_t u; } uu;
    uu.h = __builtin_amdgcn_cvt_pkrtz(a, b);
    return uu.u;
}
__device__ __forceinline__ half8 as_half8(uint4 u) {
    union { uint4 u; half8 h; } uu; uu.u = u; return uu.h;
}

// ---------------------------------------------------------------------------
// Kernel 1: QKV MFMA projection + lift (R11 champion version: X and W staged
// through LDS — the coalescing transpose matters even at reuse=1 for W).
// vT written with the sigma column permutation within each 64-token group
// (s = q*8 + nt2*4 + r <-> kv = nt2*16 + q*4 + r) so attention's PV
// B-fragments line up with in-register A-fragments.
// ---------------------------------------------------------------------------
__global__ __launch_bounds__(256, 3) void qkv_mfma(
    const float* __restrict__ Xq, const float* __restrict__ Xs,
    const float* __restrict__ Wq, const float* __restrict__ Wk,
    const float* __restrict__ Wv,
    const float* __restrict__ Wqb, const float* __restrict__ Wkb,
    const float* __restrict__ Wvb, const float* __restrict__ scale_p,
    _Float16* __restrict__ q16, _Float16* __restrict__ k16,
    _Float16* __restrict__ vT16)
{
    const int mtb = blockIdx.x;   // token tile
    const int hp  = blockIdx.y;   // head pair 0..3
    const int mat = blockIdx.z;
    const int t    = threadIdx.x;
    const int w    = t >> 6;
    const int lane = t & 63;
    const int l15  = lane & 15;
    const int quad = lane >> 4;

    __shared__ alignas(16) char smem[27648];
    __shared__ float psum[64][4];
    _Float16 (*Xsh)[72]  = (_Float16(*)[72])smem;            //  9216 B
    _Float16 (*Wsh)[72]  = (_Float16(*)[72])(smem + 9216);   // 18432 B
    _Float16 (*Osh)[136] = (_Float16(*)[136])(smem + 9216);  // alias
    _Float16 (*OshT)[72] = (_Float16(*)[72])(smem + 9216);   // alias

    const float* X    = (mat == 0) ? Xq : Xs;
    const float* W    = (mat == 0) ? Wq : (mat == 1 ? Wk : Wv);
    const float* bias = (mat == 0) ? Wqb : (mat == 1 ? Wkb : Wvb);
    const int tok0 = mtb * 64;

    floatx4 acc[4][2];
#pragma unroll
    for (int mt = 0; mt < 4; mt++)
#pragma unroll
        for (int nt = 0; nt < 2; nt++) acc[mt][nt] = (floatx4){0.f,0.f,0.f,0.f};

    float4 pxa[2], pxb[2], pwa[4], pwb[4];
#pragma unroll
    for (int ls = 0; ls < 2; ls++) {
        int g = t + 256 * ls, r = g >> 3, c = g & 7;
        const float* p = X + (size_t)(tok0 + r) * EE + c * 8;
        pxa[ls] = *(const float4*)p;
        pxb[ls] = *(const float4*)(p + 4);
    }
#pragma unroll
    for (int ls = 0; ls < 4; ls++) {
        int g = t + 256 * ls, r = g >> 3, c = g & 7;
        int head = r >> 6, j = r & 63;
        pwa[ls] = make_float4(0.f,0.f,0.f,0.f);
        pwb[ls] = make_float4(0.f,0.f,0.f,0.f);
        if (j < DM1) {
            const float* p = W + (size_t)((hp * 2 + head) * DM1 + j) * EE + c * 8;
            pwa[ls] = *(const float4*)p;
            pwb[ls] = *(const float4*)(p + 4);
        }
    }

    for (int it = 0; it < 8; it++) {
        __syncthreads();
#pragma unroll
        for (int ls = 0; ls < 2; ls++) {
            int g = t + 256 * ls, r = g >> 3, c = g & 7;
            uint4 h;
            h.x = pkh2(pxa[ls].x, pxa[ls].y); h.y = pkh2(pxa[ls].z, pxa[ls].w);
            h.z = pkh2(pxb[ls].x, pxb[ls].y); h.w = pkh2(pxb[ls].z, pxb[ls].w);
            *(uint4*)&Xsh[r][c * 8] = h;
        }
#pragma unroll
        for (int ls = 0; ls < 4; ls++) {
            int g = t + 256 * ls, r = g >> 3, c = g & 7;
            uint4 h;
            h.x = pkh2(pwa[ls].x, pwa[ls].y); h.y = pkh2(pwa[ls].z, pwa[ls].w);
            h.z = pkh2(pwb[ls].x, pwb[ls].y); h.w = pkh2(pwb[ls].z, pwb[ls].w);
            *(uint4*)&Wsh[r][c * 8] = h;
        }
        __syncthreads();
        if (it + 1 < 8) {
            int ek = (it + 1) * 64;
#pragma unroll
            for (int ls = 0; ls < 2; ls++) {
                int g = t + 256 * ls, r = g >> 3, c = g & 7;
                const float* p = X + (size_t)(tok0 + r) * EE + ek + c * 8;
                pxa[ls] = *(const float4*)p;
                pxb[ls] = *(const float4*)(p + 4);
            }
#pragma unroll
            for (int ls = 0; ls < 4; ls++) {
                int g = t + 256 * ls, r = g >> 3, c = g & 7;
                int head = r >> 6, j = r & 63;
                if (j < DM1) {
                    const float* p = W + (size_t)((hp * 2 + head) * DM1 + j) * EE + ek + c * 8;
                    pwa[ls] = *(const float4*)p;
                    pwb[ls] = *(const float4*)(p + 4);
                }
            }
        }
#pragma unroll
        for (int kk = 0; kk < 2; kk++) {
            half8 a[4];
#pragma unroll
            for (int mt = 0; mt < 4; mt++)
                a[mt] = *(const half8*)&Xsh[mt * 16 + l15][kk * 32 + quad * 8];
#pragma unroll
            for (int nt = 0; nt < 2; nt++) {
                half8 bfr = *(const half8*)&Wsh[w * 32 + nt * 16 + l15][kk * 32 + quad * 8];
#pragma unroll
                for (int mt = 0; mt < 4; mt++)
                    acc[mt][nt] = __builtin_amdgcn_mfma_f32_16x16x32_f16(
                        a[mt], bfr, acc[mt][nt], 0, 0, 0);
            }
        }
    }
    __syncthreads();   // Wsh dead -> Osh/OshT alias safe

    const float st   = 2.0f / scale_p[0];
    const float fmul = (mat == 0) ? st : 1.0f;

    float vals[4][2][4];
    float sqp[4][4];
#pragma unroll
    for (int mt = 0; mt < 4; mt++)
#pragma unroll
        for (int r = 0; r < 4; r++) sqp[mt][r] = 0.f;

#pragma unroll
    for (int mt = 0; mt < 4; mt++)
#pragma unroll
        for (int nt = 0; nt < 2; nt++) {
            int col = w * 32 + nt * 16 + l15;
            int head = col >> 6, j = col & 63;
            float bb = (j < DM1) ? bias[(hp * 2 + head) * DM1 + j] : 0.f;
#pragma unroll
            for (int r = 0; r < 4; r++) {
                float vv = acc[mt][nt][r] + bb;
                if (j >= DM1) vv = 0.f;
                vals[mt][nt][r] = vv;
                sqp[mt][r] += vv * vv;
            }
        }
#pragma unroll
    for (int mt = 0; mt < 4; mt++)
#pragma unroll
        for (int r = 0; r < 4; r++) {
            float s = sqp[mt][r];
            s += __shfl_xor(s, 1, 64); s += __shfl_xor(s, 2, 64);
            s += __shfl_xor(s, 4, 64); s += __shfl_xor(s, 8, 64);
            if (l15 == 0) psum[mt * 16 + quad * 4 + r][w] = s;
        }

    if (mat < 2) {
#pragma unroll
        for (int mt = 0; mt < 4; mt++)
#pragma unroll
            for (int nt = 0; nt < 2; nt++) {
                int col = w * 32 + nt * 16 + l15;
                int head = col >> 6, j = col & 63;
                if (j < DM1) {
                    int dc = head * 64 + 1 + j;
#pragma unroll
                    for (int r = 0; r < 4; r++)
                        Osh[mt * 16 + quad * 4 + r][dc] = (_Float16)(vals[mt][nt][r] * fmul);
                }
            }
    } else {
#pragma unroll
        for (int mt = 0; mt < 4; mt++)
#pragma unroll
            for (int nt = 0; nt < 2; nt++) {
                int col = w * 32 + nt * 16 + l15;
                uint2 pu;
                pu.x = pkh2(vals[mt][nt][0], vals[mt][nt][1]);
                pu.y = pkh2(vals[mt][nt][2], vals[mt][nt][3]);
                *(uint2*)&OshT[col][mt * 16 + quad * 4] = pu;
            }
    }
    __syncthreads();
    if (t < 64) {
        float tsA = sqrtf(psum[t][0] + psum[t][1] + 1.0f);
        float tsB = sqrtf(psum[t][2] + psum[t][3] + 1.0f);
        if (mat < 2) {
            float tm = (mat == 0) ? -st : 1.0f;
            Osh[t][0]  = (_Float16)(tsA * tm);
            Osh[t][64] = (_Float16)(tsB * tm);
        } else {
            OshT[63][t]  = (_Float16)tsA;
            OshT[127][t] = (_Float16)tsB;
        }
    }
    __syncthreads();

    const int bI = tok0 >> 11, n0 = tok0 & 2047;
    if (mat < 2) {
        _Float16* O = (mat == 0) ? q16 : k16;
#pragma unroll
        for (int ls = 0; ls < 4; ls++) {
            int s = t + 256 * ls, r = s >> 4, c = s & 15, head = c >> 3;
            size_t bh = (size_t)(bI * HH + hp * 2 + head);
            *(uint4*)&O[(bh * NN + n0 + r) * DD + (c & 7) * 8] = *(const uint4*)&Osh[r][c * 8];
        }
    } else {
        // sigma-permuted vT write: each uint4 splits into two uint2 granules
#pragma unroll
        for (int ls = 0; ls < 4; ls++) {
            int s = t + 256 * ls, df = s >> 3, c = s & 7;
            int head = df >> 6, d = df & 63;
            int rr = head * 64 + ((d + 63) & 63);   // d=0 -> row 63 (time slot)
            size_t bh = (size_t)(bI * HH + hp * 2 + head);
            uint4 v = *(const uint4*)&OshT[rr][c * 8];
            int cc = c & 3, hf = c >> 2;
            int sA = hf * 32 + ((2 * cc) & 3) * 8 + (cc >> 1) * 4;
            int sB = hf * 32 + ((2 * cc + 1) & 3) * 8 + (cc >> 1) * 4;
            _Float16* vrow = &vT16[(bh * DD + d) * NN + n0];
            *(uint2*)&vrow[sA] = make_uint2(v.x, v.y);
            *(uint2*)&vrow[sB] = make_uint2(v.z, v.w);
        }
    }
}

// ---------------------------------------------------------------------------
// Kernel 2: Lorentz flash attention (R11 champion): no-P in-register path
// (sigma V), KSP=4, grid (8,16,4)=512 blocks=2/CU, 8 iters/block,
// double-buffered K/V, one barrier/iter, 64 q-rows/wave.
// ---------------------------------------------------------------------------
__global__ __launch_bounds__(256, 2) void lorentz_attn_v14(
    const _Float16* __restrict__ q16, const _Float16* __restrict__ k16,
    const _Float16* __restrict__ vT16,
    _Float16* __restrict__ Odh, float* __restrict__ Ors)
{
    const int qt = blockIdx.x;    // 256 q-rows per block
    const int bh = blockIdx.y;
    const int ks = blockIdx.z;    // split-K quarter
    const int t    = threadIdx.x;
    const int w    = t >> 6;
    const int lane = t & 63;
    const int l15  = lane & 15;
    const int quad = lane >> 4;

    __shared__ alignas(16) char smem[36864];
    // K bufs [2][64][72] @ 0 ; VT bufs [2][64][72] @ 18432

    const _Float16* kb = k16  + (size_t)bh * NN * DD;
    const _Float16* vb = vT16 + (size_t)bh * DD * NN;
    const int base = ks * 8;

    // Q B-fragments: wave w owns q-rows qt*256 + w*64 + mt*16 + [0,16)
    half8 qb[4][2];
#pragma unroll
    for (int mt = 0; mt < 4; mt++) {
        const _Float16* qrow = q16 +
            ((size_t)bh * NN + qt * 256 + w * 64 + mt * 16 + l15) * DD;
        qb[mt][0] = *(const half8*)&qrow[quad * 8];
        qb[mt][1] = *(const half8*)&qrow[32 + quad * 8];
    }

    half8 vones;
#pragma unroll
    for (int i = 0; i < 8; i++) vones[i] = (_Float16)1.0f;

    // prefetch + commit tile 0 into buf 0
    uint4 pk[2], pv[2];
#pragma unroll
    for (int ls = 0; ls < 2; ls++) {
        int s = t + 256 * ls, r = s >> 3, c = s & 7;
        pk[ls] = *(const uint4*)&kb[((size_t)base * 64 + r) * DD + c * 8];
        pv[ls] = *(const uint4*)&vb[(size_t)r * NN + base * 64 + c * 8];
    }
#pragma unroll
    for (int ls = 0; ls < 2; ls++) {
        int s = t + 256 * ls, r = s >> 3, c = s & 7;
        *(uint4*)(smem +         (size_t)r * 144 + c * 16) = pk[ls];
        *(uint4*)(smem + 18432 + (size_t)r * 144 + c * 16) = pv[ls];
    }
    __syncthreads();

    floatx4 oacc[4][5];
#pragma unroll
    for (int mt = 0; mt < 4; mt++)
#pragma unroll
        for (int nt = 0; nt < 5; nt++) oacc[mt][nt] = (floatx4){0.f,0.f,0.f,0.f};

    for (int i = 0; i < 8; i++) {
        const int kt = base + i;
        const int buf = i & 1;
        _Float16 (*Ks)[72]  = (_Float16(*)[72])(smem + buf * 9216);
        _Float16 (*VTs)[72] = (_Float16(*)[72])(smem + 18432 + buf * 9216);

        if (i + 1 < 8) {   // prefetch next tile into registers
#pragma unroll
            for (int ls = 0; ls < 2; ls++) {
                int s = t + 256 * ls, r = s >> 3, c = s & 7;
                pk[ls] = *(const uint4*)&kb[((size_t)(kt + 1) * 64 + r) * DD + c * 8];
                pv[ls] = *(const uint4*)&vb[(size_t)r * NN + (kt + 1) * 64 + c * 8];
            }
        }

#pragma unroll
        for (int half = 0; half < 2; half++) {
            // ---- S^T for this kv-half (nt = half*2 + nt2) ----
            floatx4 sacc[2][4];
#pragma unroll
            for (int nt2 = 0; nt2 < 2; nt2++) {
#pragma unroll
                for (int mt = 0; mt < 4; mt++) sacc[nt2][mt] = (floatx4){0.f,0.f,0.f,0.f};
                const int nt = half * 2 + nt2;
#pragma unroll
                for (int kk = 0; kk < 2; kk++) {
                    half8 kf = *(const half8*)&Ks[nt * 16 + l15][kk * 32 + quad * 8];
#pragma unroll
                    for (int mt = 0; mt < 4; mt++)
                        sacc[nt2][mt] = __builtin_amdgcn_mfma_f32_16x16x32_f16(
                            kf, qb[mt][kk], sacc[nt2][mt], 0, 0, 0);
                }
            }
            // ---- exp + pack in-register: this IS the PV A-fragment ----
            half8 pa[4];
#pragma unroll
            for (int mt = 0; mt < 4; mt++) {
                uint4 u;
                u.x = pkh2(__expf(sacc[0][mt][0]), __expf(sacc[0][mt][1]));
                u.y = pkh2(__expf(sacc[0][mt][2]), __expf(sacc[0][mt][3]));
                u.z = pkh2(__expf(sacc[1][mt][0]), __expf(sacc[1][mt][1]));
                u.w = pkh2(__expf(sacc[1][mt][2]), __expf(sacc[1][mt][3]));
                pa[mt] = as_half8(u);
            }
            // ---- O += P . [V_sigma ; 1] for this half (K=32) ----
#pragma unroll
            for (int nt = 0; nt < 4; nt++) {
                half8 vf = *(const half8*)&VTs[nt * 16 + l15][half * 32 + quad * 8];
#pragma unroll
                for (int mt = 0; mt < 4; mt++)
                    oacc[mt][nt] = __builtin_amdgcn_mfma_f32_16x16x32_f16(
                        pa[mt], vf, oacc[mt][nt], 0, 0, 0);
            }
#pragma unroll
            for (int mt = 0; mt < 4; mt++)
                oacc[mt][4] = __builtin_amdgcn_mfma_f32_16x16x32_f16(
                    pa[mt], vones, oacc[mt][4], 0, 0, 0);
        }

        // ---- commit next tile into the OTHER buffer, single barrier ----
        if (i + 1 < 8) {
            char* kd = smem +         (1 - buf) * 9216;
            char* vd = smem + 18432 + (1 - buf) * 9216;
#pragma unroll
            for (int ls = 0; ls < 2; ls++) {
                int s = t + 256 * ls, r = s >> 3, c = s & 7;
                *(uint4*)(kd + (size_t)r * 144 + c * 16) = pk[ls];
                *(uint4*)(vd + (size_t)r * 144 + c * 16) = pv[ls];
            }
        }
        __syncthreads();
    }

    // ---- coalesced f16 dump via per-wave f32 slab (reuse K/V LDS) ----
    const size_t obase = (((size_t)ks * 16 + bh) * NN + qt * 256 + w * 64);
    float* slab = (float*)(smem + w * 4608);   // 16x68 f32 = 4352 B per wave
#pragma unroll
    for (int mt = 0; mt < 4; mt++) {
#pragma unroll
        for (int nt = 0; nt < 4; nt++)
#pragma unroll
            for (int r = 0; r < 4; r++)
                slab[(quad * 4 + r) * 68 + nt * 16 + l15] = oacc[mt][nt][r];
        // wave-local slab; compiler inserts lgkm waits
#pragma unroll
        for (int i = 0; i < 4; i++) {
            int s = lane + 64 * i, row = s >> 4, c4 = (s & 15) * 4;
            float4 v = *(const float4*)&slab[row * 68 + c4];
            uint2 pu;
            pu.x = pkh2(v.x, v.y);
            pu.y = pkh2(v.z, v.w);
            *(uint2*)&Odh[(obase + mt * 16 + row) * 64 + c4] = pu;
        }
        if (l15 == 0) {
#pragma unroll
            for (int r = 0; r < 4; r++)
                Ors[obase + mt * 16 + quad * 4 + r] = oacc[mt][4][r];
        }
    }
}

// ---------------------------------------------------------------------------
// Kernel 3: 4-way split-K merge + per-head Lorentzian centroid + head mean +
// final centroid. One wave per token; lane = d.
// ---------------------------------------------------------------------------
__global__ __launch_bounds__(256) void merge_centroid(
    const _Float16* __restrict__ Odh, const float* __restrict__ Ors,
    float* __restrict__ out)
{
    const int t    = threadIdx.x;
    const int tok  = blockIdx.x * 4 + (t >> 6);
    const int lane = t & 63;
    const int b = tok >> 11;
    const int n = tok & 2047;

    float m = 0.f;
#pragma unroll
    for (int h = 0; h < HH; h++) {
        const size_t bh = (size_t)(b * HH + h);
        float o = 0.f, rs = 0.f;
#pragma unroll
        for (int ksp = 0; ksp < KSP; ksp++) {
            const size_t row = ((size_t)ksp * 16 + bh) * NN + n;
            o  += (float)Odh[row * 64 + lane];
            rs += Ors[row];
        }
        float a  = o / rs;
        float ssq = a * a;
#pragma unroll
        for (int off = 32; off > 0; off >>= 1)
            ssq += __shfl_xor(ssq, off, 64);
        float a0 = __shfl(a, 0, 64);           // d=0 = time
        float inner = ssq - 2.0f * a0 * a0;
        float f = rsqrtf(fmaxf(fabsf(inner), 1e-8f));
        m += a * f;
    }
    m *= 0.125f;

    float sq = m * m;
#pragma unroll
    for (int off = 32; off > 0; off >>= 1)
        sq += __shfl_xor(sq, off, 64);
    float m0 = __shfl(m, 0, 64);
    float inner = sq - 2.0f * m0 * m0;
    float f = rsqrtf(fmaxf(fabsf(inner), 1e-8f));
    out[(size_t)tok * DD + lane] = m * f;
}

extern "C" void kernel_launch(void* const* d_in, const int* in_sizes, int n_in,
                              void* d_out, int out_size, void* d_ws, size_t ws_size,
                              hipStream_t stream)
{
    const float* Xq  = (const float*)d_in[0];
    const float* Xs  = (const float*)d_in[1];
    const float* Wq  = (const float*)d_in[2];
    const float* Wqb = (const float*)d_in[3];
    const float* Wk  = (const float*)d_in[4];
    const float* Wkb = (const float*)d_in[5];
    const float* Wv  = (const float*)d_in[6];
    const float* Wvb = (const float*)d_in[7];
    const float* sc  = (const float*)d_in[8];
    float* out = (float*)d_out;

    const size_t QSZ = (size_t)BB * HH * NN * DD;   // 2,097,152 halves
    _Float16* q16  = (_Float16*)d_ws;
    _Float16* k16  = q16 + QSZ;
    _Float16* vT16 = k16 + QSZ;                     // 12 MB f16
    _Float16* Odh  = vT16 + QSZ;                    // 4*16*2048*64 f16 = 16.8 MB
    float* Ors = (float*)(Odh + (size_t)KSP * 16 * NN * 64);  // 512 KB

    qkv_mfma<<<dim3(64, 4, 3), 256, 0, stream>>>(Xq, Xs, Wq, Wk, Wv,
                                                 Wqb, Wkb, Wvb, sc,
                                                 q16, k16, vT16);
    lorentz_attn_v14<<<dim3(8, 16, KSP), 256, 0, stream>>>(q16, k16, vT16, Odh, Ors);
    merge_centroid<<<(BB * NN) / 4, 256, 0, stream>>>(Odh, Ors, out);
}